// Round 2
// baseline (1635.581 us; speedup 1.0000x reference)
//
#include <hip/hip_runtime.h>

#define NROWS 16384
#define KCODES 8192
#define DDIM 256
#define MARGIN 5.0f

typedef __attribute__((ext_vector_type(8))) short short8;
typedef __attribute__((ext_vector_type(4))) float f32x4;

// ---------------- helpers ----------------
__device__ inline unsigned short f2bf(float x) {
    unsigned u = __float_as_uint(x);
    return (unsigned short)((u + 0x7FFFu + ((u >> 16) & 1u)) >> 16);  // RNE
}

// ---------------- init ----------------
__global__ void k_init(unsigned long long* best, unsigned* amin, float* accum) {
    int i = blockIdx.x * blockDim.x + threadIdx.x;
    if (i < NROWS) { best[i] = 0xFFFFFFFFFFFFFFFFull; amin[i] = 0x7F800000u; }
    if (i == 0) accum[0] = 0.0f;
}

// ---------------- row sum-of-squares ----------------
__global__ void k_sumsq(const float* __restrict__ in, float* __restrict__ out, int rows) {
    int row = blockIdx.x * 4 + (threadIdx.x >> 6);
    int lane = threadIdx.x & 63;
    if (row >= rows) return;
    const float4 v = *reinterpret_cast<const float4*>(in + (size_t)row * DDIM + lane * 4);
    float s = v.x * v.x + v.y * v.y + v.z * v.z + v.w * v.w;
    #pragma unroll
    for (int off = 32; off > 0; off >>= 1) s += __shfl_down(s, off);
    if (lane == 0) out[row] = s;
}

// ---------------- MFMA screen + fused exact rescore ----------------
// approx dist(n,k) = z2[n] + e2[k] - 2*dot_bf16(z[n],cb[k]); exact rescore within MARGIN.
__global__ __launch_bounds__(256) void k_screen(
    const float* __restrict__ z, const float* __restrict__ cbp,
    const float* __restrict__ z2g, const float* __restrict__ e2g,
    unsigned* __restrict__ amin, unsigned long long* __restrict__ best)
{
    // chunked LDS: A = 16 chunks of 1KB, B = 16 chunks of 1KB (32 KB total).
    // A chunk c, slot s (16B): z row (c>>1)*16 + (s&15), k = ks*64 + (c&1)*32 + (s>>4)*8 .. +8
    __shared__ __align__(16) short lds[16384];
    char* ldsb = (char*)lds;

    const int tid = threadIdx.x;
    const int lane = tid & 63;
    const int wave = tid >> 6;
    const int wm = wave & 1;
    const int wn = wave >> 1;
    const int lhi = lane >> 4;
    const int llo = lane & 15;
    const int sc = tid >> 6;   // staging chunk base
    const int sl = tid & 63;   // staging slot

    // supertile swizzle: 8x8 blocks per supertile; 16 rt-groups x 8 ct-groups
    const int bx = blockIdx.x;
    const int st = bx >> 6;
    const int wi = bx & 63;
    const int rt = (st & 15) * 8 + (wi >> 3);   // 0..127
    const int ct = (st >> 4) * 8 + (wi & 7);    // 0..63
    const int row0 = rt * 128;
    const int col0 = ct * 128;

    f32x4 acc[4][4];
    const f32x4 zero = {0.f, 0.f, 0.f, 0.f};
    #pragma unroll
    for (int i = 0; i < 4; ++i)
        #pragma unroll
        for (int j = 0; j < 4; ++j) acc[i][j] = zero;

    for (int ks = 0; ks < 4; ++ks) {
        if (ks) __syncthreads();  // previous compute done before overwrite
        // stage A and B (fp32 -> bf16, conflict-free contiguous ds_write_b128)
        #pragma unroll
        for (int i = 0; i < 4; ++i) {
            const int c = sc + i * 4;                       // 0..15
            const int rr = (c >> 1) * 16 + (sl & 15);
            const int k0 = ks * 64 + (c & 1) * 32 + (sl >> 4) * 8;
            const float4* ga = reinterpret_cast<const float4*>(z + (size_t)(row0 + rr) * DDIM + k0);
            const float4 a0 = ga[0], a1 = ga[1];
            const float4* gb = reinterpret_cast<const float4*>(cbp + (size_t)(col0 + rr) * DDIM + k0);
            const float4 b0 = gb[0], b1 = gb[1];
            short8 pa, pb;
            pa[0] = f2bf(a0.x); pa[1] = f2bf(a0.y); pa[2] = f2bf(a0.z); pa[3] = f2bf(a0.w);
            pa[4] = f2bf(a1.x); pa[5] = f2bf(a1.y); pa[6] = f2bf(a1.z); pa[7] = f2bf(a1.w);
            pb[0] = f2bf(b0.x); pb[1] = f2bf(b0.y); pb[2] = f2bf(b0.z); pb[3] = f2bf(b0.w);
            pb[4] = f2bf(b1.x); pb[5] = f2bf(b1.y); pb[6] = f2bf(b1.z); pb[7] = f2bf(b1.w);
            *reinterpret_cast<short8*>(ldsb + c * 1024 + sl * 16) = pa;
            *reinterpret_cast<short8*>(ldsb + 16384 + c * 1024 + sl * 16) = pb;
        }
        __syncthreads();
        // compute: 2 k-subtiles of 32, 16 MFMAs each
        #pragma unroll
        for (int kk = 0; kk < 2; ++kk) {
            short8 af[4], bf[4];
            #pragma unroll
            for (int f = 0; f < 4; ++f) {
                const int ca = (wm * 4 + f) * 2 + kk;
                af[f] = *reinterpret_cast<const short8*>(ldsb + ca * 1024 + lane * 16);
                const int cc = (wn * 4 + f) * 2 + kk;
                bf[f] = *reinterpret_cast<const short8*>(ldsb + 16384 + cc * 1024 + lane * 16);
            }
            #pragma unroll
            for (int fm = 0; fm < 4; ++fm)
                #pragma unroll
                for (int fn = 0; fn < 4; ++fn)
                    acc[fm][fn] = __builtin_amdgcn_mfma_f32_16x16x32_bf16(af[fm], bf[fn], acc[fm][fn], 0, 0, 0);
        }
    }

    // epilogue: per-row approx min + margin-qualified exact rescore
    const int rbase = row0 + wm * 64;
    const int cbase = col0 + wn * 64;
    float e2c[4];
    #pragma unroll
    for (int fn = 0; fn < 4; ++fn) e2c[fn] = e2g[cbase + fn * 16 + llo];

    #pragma unroll
    for (int fm = 0; fm < 4; ++fm) {
        #pragma unroll
        for (int rg = 0; rg < 4; ++rg) {
            const int grow = rbase + fm * 16 + lhi * 4 + rg;
            const float z2v = z2g[grow];
            float d[4];
            #pragma unroll
            for (int fn = 0; fn < 4; ++fn) d[fn] = z2v + e2c[fn] - 2.0f * acc[fm][fn][rg];
            float m = fminf(fminf(d[0], d[1]), fminf(d[2], d[3]));
            #pragma unroll
            for (int off = 1; off < 16; off <<= 1) m = fminf(m, __shfl_xor(m, off));
            unsigned old = 0x7F800000u;
            if (llo == 0) old = atomicMin(&amin[grow], __float_as_uint(m));
            old = (unsigned)__shfl((int)old, lane & 48);
            const float thr = fminf(__uint_as_float(old), m) + MARGIN;
            #pragma unroll
            for (int fn = 0; fn < 4; ++fn) {
                if (d[fn] <= thr) {
                    const int gcol = cbase + fn * 16 + llo;
                    const float4* av = reinterpret_cast<const float4*>(z + (size_t)grow * DDIM);
                    const float4* bv = reinterpret_cast<const float4*>(cbp + (size_t)gcol * DDIM);
                    float dot = 0.f;
                    #pragma unroll 8
                    for (int j = 0; j < 64; ++j) {
                        const float4 xa = av[j], xb = bv[j];
                        dot = fmaf(xa.x, xb.x, fmaf(xa.y, xb.y, fmaf(xa.z, xb.z, fmaf(xa.w, xb.w, dot))));
                    }
                    const float de = z2v + e2c[fn] - 2.0f * dot;
                    const unsigned long long key =
                        ((unsigned long long)__float_as_uint(de) << 32) | (unsigned)gcol;
                    atomicMin(&best[grow], key);
                }
            }
        }
    }
}

// ---------------- gather + z_st + loss ----------------
__global__ void k_gather(const float* __restrict__ z, const float* __restrict__ cbp,
                         const unsigned long long* __restrict__ best,
                         float* __restrict__ out, float* __restrict__ accum)
{
    const int row = blockIdx.x * 4 + (threadIdx.x >> 6);
    const int lane = threadIdx.x & 63;
    const unsigned k = (unsigned)(best[row] & 0xFFFFFFFFull);
    const float4 ze = *reinterpret_cast<const float4*>(z + (size_t)row * DDIM + lane * 4);
    const float4 cq = *reinterpret_cast<const float4*>(cbp + (size_t)k * DDIM + lane * 4);
    float4 zst;
    zst.x = ze.x + (cq.x - ze.x); zst.y = ze.y + (cq.y - ze.y);
    zst.z = ze.z + (cq.z - ze.z); zst.w = ze.w + (cq.w - ze.w);
    *reinterpret_cast<float4*>(out + (size_t)row * DDIM + lane * 4) = zst;
    const float dx = cq.x - ze.x, dy = cq.y - ze.y, dz = cq.z - ze.z, dw = cq.w - ze.w;
    float s = dx * dx + dy * dy + dz * dz + dw * dw;
    #pragma unroll
    for (int off = 32; off > 0; off >>= 1) s += __shfl_down(s, off);
    if (lane == 0) {
        atomicAdd(accum, s);
        out[(size_t)NROWS * DDIM + row] = (float)k;
    }
}

// ---------------- final scalars ----------------
__global__ void k_final(const float* __restrict__ accum, float* __restrict__ out) {
    const float m = accum[0] / (float)(NROWS * DDIM);
    out[(size_t)NROWS * DDIM + NROWS + 0] = m;  // commit
    out[(size_t)NROWS * DDIM + NROWS + 1] = m;  // codebook_loss
}

extern "C" void kernel_launch(void* const* d_in, const int* in_sizes, int n_in,
                              void* d_out, int out_size, void* d_ws, size_t ws_size,
                              hipStream_t stream)
{
    const float* z  = (const float*)d_in[0];   // (16,32,32,256) fp32
    const float* cb = (const float*)d_in[1];   // (8192,256) fp32
    float* out = (float*)d_out;

    char* ws = (char*)d_ws;
    unsigned long long* best = (unsigned long long*)ws;          // 131072 B
    float* e2    = (float*)(ws + 131072);                        // 32768 B
    float* z2    = (float*)(ws + 131072 + 32768);                // 65536 B
    unsigned* amin = (unsigned*)(ws + 131072 + 32768 + 65536);   // 65536 B
    float* accum = (float*)(ws + 131072 + 32768 + 65536 + 65536);

    k_init<<<(NROWS + 255) / 256, 256, 0, stream>>>(best, amin, accum);
    k_sumsq<<<KCODES / 4, 256, 0, stream>>>(cb, e2, KCODES);
    k_sumsq<<<NROWS / 4, 256, 0, stream>>>(z, z2, NROWS);
    k_screen<<<8192, 256, 0, stream>>>(z, cb, z2, e2, amin, best);
    k_gather<<<NROWS / 4, 256, 0, stream>>>(z, cb, best, out, accum);
    k_final<<<1, 1, 0, stream>>>(accum, out);
}

// Round 3
// 509.828 us; speedup vs baseline: 3.2081x; 3.2081x over previous
//
#include <hip/hip_runtime.h>

#define NROWS 16384
#define KCODES 8192
#define DDIM 256
#define MARGIN 2.0f
#define BLKLIST 256

typedef __attribute__((ext_vector_type(8))) short short8;
typedef __attribute__((ext_vector_type(4))) float f32x4;

// ---------------- helpers ----------------
__device__ inline unsigned short f2bf(float x) {
    unsigned u = __float_as_uint(x);
    return (unsigned short)((u + 0x7FFFu + ((u >> 16) & 1u)) >> 16);  // RNE
}

__device__ inline void exact_rescore(const float* __restrict__ z, const float* __restrict__ cb,
                                     const float* __restrict__ z2g, const float* __restrict__ e2g,
                                     int grow, int gcol, unsigned long long* best) {
    const float4* av = reinterpret_cast<const float4*>(z + (size_t)grow * DDIM);
    const float4* bv = reinterpret_cast<const float4*>(cb + (size_t)gcol * DDIM);
    float dot = 0.f;
    #pragma unroll 8
    for (int j = 0; j < 64; ++j) {
        const float4 xa = av[j], xb = bv[j];
        dot = fmaf(xa.x, xb.x, fmaf(xa.y, xb.y, fmaf(xa.z, xb.z, fmaf(xa.w, xb.w, dot))));
    }
    const float de = z2g[grow] + e2g[gcol] - 2.0f * dot;
    const unsigned long long key =
        ((unsigned long long)__float_as_uint(de) << 32) | (unsigned)gcol;
    atomicMin(best + grow, key);
}

// ---------------- init ----------------
__global__ void k_init(unsigned long long* best, unsigned* amin, float* accum, unsigned* counter) {
    int i = blockIdx.x * blockDim.x + threadIdx.x;
    if (i < NROWS) { best[i] = 0xFFFFFFFFFFFFFFFFull; amin[i] = 0x7F800000u; }
    if (i == 0) { accum[0] = 0.0f; counter[0] = 0u; }
}

// ---------------- row sum-of-squares ----------------
__global__ void k_sumsq(const float* __restrict__ in, float* __restrict__ out, int rows) {
    int row = blockIdx.x * 4 + (threadIdx.x >> 6);
    int lane = threadIdx.x & 63;
    if (row >= rows) return;
    const float4 v = *reinterpret_cast<const float4*>(in + (size_t)row * DDIM + lane * 4);
    float s = v.x * v.x + v.y * v.y + v.z * v.z + v.w * v.w;
    #pragma unroll
    for (int off = 32; off > 0; off >>= 1) s += __shfl_down(s, off);
    if (lane == 0) out[row] = s;
}

// ---------------- MFMA screen: emit near-min candidates ----------------
__global__ __launch_bounds__(256) void k_screen(
    const float* __restrict__ z, const float* __restrict__ cbp,
    const float* __restrict__ z2g, const float* __restrict__ e2g,
    unsigned* amin, unsigned long long* best,
    unsigned* counter, unsigned* list, unsigned C)
{
    __shared__ __align__(16) short lds[16384];
    char* ldsb = (char*)lds;
    __shared__ unsigned gbase_s;

    const int tid = threadIdx.x;
    const int lane = tid & 63;
    const int wave = tid >> 6;
    const int wm = wave & 1;
    const int wn = wave >> 1;
    const int lhi = lane >> 4;
    const int llo = lane & 15;
    const int sc = tid >> 6;
    const int sl = tid & 63;

    const int bx = blockIdx.x;
    const int st = bx >> 6;
    const int wi = bx & 63;
    const int rt = (st & 15) * 8 + (wi >> 3);   // 0..127
    const int ct = (st >> 4) * 8 + (wi & 7);    // 0..63
    const int row0 = rt * 128;
    const int col0 = ct * 128;

    f32x4 acc[4][4];
    const f32x4 zero = {0.f, 0.f, 0.f, 0.f};
    #pragma unroll
    for (int i = 0; i < 4; ++i)
        #pragma unroll
        for (int j = 0; j < 4; ++j) acc[i][j] = zero;

    for (int ks = 0; ks < 4; ++ks) {
        if (ks) __syncthreads();
        #pragma unroll
        for (int i = 0; i < 4; ++i) {
            const int c = sc + i * 4;
            const int rr = (c >> 1) * 16 + (sl & 15);
            const int k0 = ks * 64 + (c & 1) * 32 + (sl >> 4) * 8;
            const float4* ga = reinterpret_cast<const float4*>(z + (size_t)(row0 + rr) * DDIM + k0);
            const float4 a0 = ga[0], a1 = ga[1];
            const float4* gb = reinterpret_cast<const float4*>(cbp + (size_t)(col0 + rr) * DDIM + k0);
            const float4 b0 = gb[0], b1 = gb[1];
            short8 pa, pb;
            pa[0] = f2bf(a0.x); pa[1] = f2bf(a0.y); pa[2] = f2bf(a0.z); pa[3] = f2bf(a0.w);
            pa[4] = f2bf(a1.x); pa[5] = f2bf(a1.y); pa[6] = f2bf(a1.z); pa[7] = f2bf(a1.w);
            pb[0] = f2bf(b0.x); pb[1] = f2bf(b0.y); pb[2] = f2bf(b0.z); pb[3] = f2bf(b0.w);
            pb[4] = f2bf(b1.x); pb[5] = f2bf(b1.y); pb[6] = f2bf(b1.z); pb[7] = f2bf(b1.w);
            *reinterpret_cast<short8*>(ldsb + c * 1024 + sl * 16) = pa;
            *reinterpret_cast<short8*>(ldsb + 16384 + c * 1024 + sl * 16) = pb;
        }
        __syncthreads();
        #pragma unroll
        for (int kk = 0; kk < 2; ++kk) {
            short8 af[4], bf[4];
            #pragma unroll
            for (int f = 0; f < 4; ++f) {
                const int ca = (wm * 4 + f) * 2 + kk;
                af[f] = *reinterpret_cast<const short8*>(ldsb + ca * 1024 + lane * 16);
                const int cc = (wn * 4 + f) * 2 + kk;
                bf[f] = *reinterpret_cast<const short8*>(ldsb + 16384 + cc * 1024 + lane * 16);
            }
            #pragma unroll
            for (int fm = 0; fm < 4; ++fm)
                #pragma unroll
                for (int fn = 0; fn < 4; ++fn)
                    acc[fm][fn] = __builtin_amdgcn_mfma_f32_16x16x32_bf16(af[fm], bf[fn], acc[fm][fn], 0, 0, 0);
        }
    }

    // ---- epilogue ----
    __syncthreads();                       // GEMM LDS reads done; reuse LDS
    float* rowmin = (float*)ldsb;          // [2][128]
    float* thrbuf = (float*)(ldsb + 1024); // [128]
    unsigned* lcnt = (unsigned*)(ldsb + 2048);
    unsigned* llist = (unsigned*)(ldsb + 2064);   // BLKLIST entries

    if (tid == 0) *lcnt = 0u;
    const int cbase = col0 + wn * 64;
    float e2c[4];
    #pragma unroll
    for (int fn = 0; fn < 4; ++fn) e2c[fn] = e2g[cbase + fn * 16 + llo];

    // pass 1: per-row block-local min
    #pragma unroll
    for (int fm = 0; fm < 4; ++fm) {
        #pragma unroll
        for (int rg = 0; rg < 4; ++rg) {
            const int rl_ = wm * 64 + fm * 16 + lhi * 4 + rg;
            const float z2v = z2g[row0 + rl_];
            float m = z2v + e2c[0] - 2.0f * acc[fm][0][rg];
            #pragma unroll
            for (int fn = 1; fn < 4; ++fn)
                m = fminf(m, z2v + e2c[fn] - 2.0f * acc[fm][fn][rg]);
            #pragma unroll
            for (int off = 1; off < 16; off <<= 1) m = fminf(m, __shfl_xor(m, off));
            if (llo == 0) rowmin[wn * 128 + rl_] = m;
        }
    }
    __syncthreads();
    if (tid < 128) {
        const float m2 = fminf(rowmin[tid], rowmin[128 + tid]);
        const unsigned cur = amin[row0 + tid];
        unsigned old = cur;
        if (__float_as_uint(m2) < cur) old = atomicMin(&amin[row0 + tid], __float_as_uint(m2));
        thrbuf[tid] = fminf(__uint_as_float(old), m2) + MARGIN;
    }
    __syncthreads();

    // pass 2: emit candidates to LDS list
    #pragma unroll
    for (int fm = 0; fm < 4; ++fm) {
        #pragma unroll
        for (int rg = 0; rg < 4; ++rg) {
            const int rl_ = wm * 64 + fm * 16 + lhi * 4 + rg;
            const int grow = row0 + rl_;
            const float z2v = z2g[grow];
            const float thr = thrbuf[rl_];
            #pragma unroll
            for (int fn = 0; fn < 4; ++fn) {
                const float d = z2v + e2c[fn] - 2.0f * acc[fm][fn][rg];
                if (d <= thr) {
                    const unsigned v = ((unsigned)grow << 13) | (unsigned)(cbase + fn * 16 + llo);
                    const unsigned slot = atomicAdd(lcnt, 1u);
                    if (slot < BLKLIST) llist[slot] = v;
                    else exact_rescore(z, cbp, z2g, e2g, grow, v & 8191u, best);
                }
            }
        }
    }
    __syncthreads();
    const unsigned bc = min(*lcnt, (unsigned)BLKLIST);
    if (tid == 0 && bc) gbase_s = atomicAdd(counter, bc);
    __syncthreads();
    for (unsigned i = tid; i < bc; i += 256) {
        const unsigned v = llist[i];
        const unsigned slot = gbase_s + i;
        if (slot < C) list[slot] = v;
        else exact_rescore(z, cbp, z2g, e2g, (int)(v >> 13), (int)(v & 8191u), best);
    }
}

// ---------------- exact rescore of candidate list (wave per candidate) ----------------
__global__ __launch_bounds__(256) void k_rescore(
    const float* __restrict__ z, const float* __restrict__ cbp,
    const float* __restrict__ z2g, const float* __restrict__ e2g,
    const unsigned* __restrict__ list, const unsigned* __restrict__ counter, unsigned C,
    unsigned long long* best)
{
    const unsigned n = min(counter[0], C);
    const unsigned wid = (blockIdx.x * blockDim.x + threadIdx.x) >> 6;
    const unsigned nw = (gridDim.x * blockDim.x) >> 6;
    const int lane = threadIdx.x & 63;
    for (unsigned i = wid; i < n; i += nw) {
        const unsigned v = list[i];
        const unsigned row = v >> 13, col = v & 8191u;
        const float4 a = *reinterpret_cast<const float4*>(z + (size_t)row * DDIM + lane * 4);
        const float4 b = *reinterpret_cast<const float4*>(cbp + (size_t)col * DDIM + lane * 4);
        float s = fmaf(a.x, b.x, fmaf(a.y, b.y, fmaf(a.z, b.z, a.w * b.w)));
        #pragma unroll
        for (int off = 1; off < 64; off <<= 1) s += __shfl_xor(s, off);
        if (lane == 0) {
            const float de = z2g[row] + e2g[col] - 2.0f * s;
            const unsigned long long key =
                ((unsigned long long)__float_as_uint(de) << 32) | col;
            atomicMin(&best[row], key);
        }
    }
}

// ---------------- gather + z_st + loss ----------------
__global__ __launch_bounds__(1024) void k_gather(
    const float* __restrict__ z, const float* __restrict__ cbp,
    const unsigned long long* __restrict__ best,
    float* __restrict__ out, float* __restrict__ accum)
{
    __shared__ float wsum[16];
    const int tid = threadIdx.x;
    const int row = blockIdx.x * 16 + (tid >> 6);
    const int lane = tid & 63;
    const unsigned k = (unsigned)(best[row] & 0xFFFFFFFFull);
    const float4 ze = *reinterpret_cast<const float4*>(z + (size_t)row * DDIM + lane * 4);
    const float4 cq = *reinterpret_cast<const float4*>(cbp + (size_t)k * DDIM + lane * 4);
    float4 zst;
    zst.x = ze.x + (cq.x - ze.x); zst.y = ze.y + (cq.y - ze.y);
    zst.z = ze.z + (cq.z - ze.z); zst.w = ze.w + (cq.w - ze.w);
    *reinterpret_cast<float4*>(out + (size_t)row * DDIM + lane * 4) = zst;
    const float dx = cq.x - ze.x, dy = cq.y - ze.y, dz = cq.z - ze.z, dw = cq.w - ze.w;
    float s = dx * dx + dy * dy + dz * dz + dw * dw;
    #pragma unroll
    for (int off = 32; off > 0; off >>= 1) s += __shfl_down(s, off);
    if (lane == 0) {
        wsum[tid >> 6] = s;
        out[(size_t)NROWS * DDIM + row] = (float)k;
    }
    __syncthreads();
    if (tid == 0) {
        float tot = 0.f;
        #pragma unroll
        for (int i = 0; i < 16; ++i) tot += wsum[i];
        atomicAdd(accum, tot);
    }
}

// ---------------- final scalars ----------------
__global__ void k_final(const float* __restrict__ accum, float* __restrict__ out) {
    const float m = accum[0] / (float)(NROWS * DDIM);
    out[(size_t)NROWS * DDIM + NROWS + 0] = m;
    out[(size_t)NROWS * DDIM + NROWS + 1] = m;
}

extern "C" void kernel_launch(void* const* d_in, const int* in_sizes, int n_in,
                              void* d_out, int out_size, void* d_ws, size_t ws_size,
                              hipStream_t stream)
{
    const float* z  = (const float*)d_in[0];
    const float* cb = (const float*)d_in[1];
    float* out = (float*)d_out;

    char* ws = (char*)d_ws;
    unsigned long long* best = (unsigned long long*)ws;            // 131072 B
    unsigned* amin = (unsigned*)(ws + 131072);                     // 65536 B
    float* e2    = (float*)(ws + 131072 + 65536);                  // 32768 B
    float* z2    = (float*)(ws + 131072 + 65536 + 32768);          // 65536 B
    float* accum   = (float*)(ws + 294912);
    unsigned* counter = (unsigned*)(ws + 294916);
    unsigned* list = (unsigned*)(ws + 295936);
    unsigned C = 0;
    if (ws_size > 295936 + 16) {
        size_t c = (ws_size - 295936) / 4;
        if (c > 4194304) c = 4194304;   // cap 16 MB
        C = (unsigned)c;
    }

    k_init<<<(NROWS + 255) / 256, 256, 0, stream>>>(best, amin, accum, counter);
    k_sumsq<<<KCODES / 4, 256, 0, stream>>>(cb, e2, KCODES);
    k_sumsq<<<NROWS / 4, 256, 0, stream>>>(z, z2, NROWS);
    k_screen<<<8192, 256, 0, stream>>>(z, cb, z2, e2, amin, best, counter, list, C);
    k_rescore<<<1024, 256, 0, stream>>>(z, cb, z2, e2, list, counter, C, best);
    k_gather<<<NROWS / 16, 1024, 0, stream>>>(z, cb, best, out, accum);
    k_final<<<1, 1, 0, stream>>>(accum, out);
}

// Round 4
// 316.975 us; speedup vs baseline: 5.1600x; 1.6084x over previous
//
#include <hip/hip_runtime.h>

#define NROWS 16384
#define KCODES 8192
#define DDIM 256
#define MARGIN 2.0f
#define BLKLIST 256

typedef __attribute__((ext_vector_type(8))) short short8;
typedef __attribute__((ext_vector_type(4))) float f32x4;

// ---------------- helpers ----------------
__device__ inline unsigned short f2bf(float x) {
    unsigned u = __float_as_uint(x);
    return (unsigned short)((u + 0x7FFFu + ((u >> 16) & 1u)) >> 16);  // RNE
}

__device__ inline void gload16(const void* g, void* l) {
    __builtin_amdgcn_global_load_lds(
        (const __attribute__((address_space(1))) unsigned char*)g,
        (__attribute__((address_space(3))) unsigned char*)l, 16, 0, 0);
}

__device__ inline void exact_rescore(const float* __restrict__ z, const float* __restrict__ cb,
                                     const float* __restrict__ z2g, const float* __restrict__ e2g,
                                     int grow, int gcol, unsigned long long* best) {
    const float4* av = reinterpret_cast<const float4*>(z + (size_t)grow * DDIM);
    const float4* bv = reinterpret_cast<const float4*>(cb + (size_t)gcol * DDIM);
    float dot = 0.f;
    #pragma unroll 8
    for (int j = 0; j < 64; ++j) {
        const float4 xa = av[j], xb = bv[j];
        dot = fmaf(xa.x, xb.x, fmaf(xa.y, xb.y, fmaf(xa.z, xb.z, fmaf(xa.w, xb.w, dot))));
    }
    const float de = z2g[grow] + e2g[gcol] - 2.0f * dot;
    const unsigned long long key =
        ((unsigned long long)__float_as_uint(de) << 32) | (unsigned)gcol;
    atomicMin(best + grow, key);
}

// ---------------- init ----------------
__global__ void k_init(unsigned long long* best, unsigned* amin, float* accum, unsigned* counter) {
    int i = blockIdx.x * blockDim.x + threadIdx.x;
    if (i < NROWS) { best[i] = 0xFFFFFFFFFFFFFFFFull; amin[i] = 0x7F800000u; }
    if (i == 0) { accum[0] = 0.0f; counter[0] = 0u; }
}

// ---------------- convert fp32 -> bf16 pre-tiled fragment layout + fused sumsq ----------------
// chunk (g, kb2): 1 KB, slot s: row g*16 + (s&15), k = kb2*32 + (s>>4)*8 .. +8
__global__ __launch_bounds__(256) void k_convert(
    const float* __restrict__ in, unsigned short* __restrict__ outt,
    float* __restrict__ sumsq, int ngroups)
{
    const int g = blockIdx.x * 4 + (threadIdx.x >> 6);
    const int lane = threadIdx.x & 63;
    if (g >= ngroups) return;
    const int row = g * 16 + (lane & 15);
    const int ko = (lane >> 4) * 8;
    float ss = 0.f;
    #pragma unroll
    for (int kb2 = 0; kb2 < 8; ++kb2) {
        const float4* src = reinterpret_cast<const float4*>(in + (size_t)row * DDIM + kb2 * 32 + ko);
        const float4 a = src[0], b = src[1];
        ss += a.x * a.x + a.y * a.y + a.z * a.z + a.w * a.w
            + b.x * b.x + b.y * b.y + b.z * b.z + b.w * b.w;
        short8 p;
        p[0] = (short)f2bf(a.x); p[1] = (short)f2bf(a.y); p[2] = (short)f2bf(a.z); p[3] = (short)f2bf(a.w);
        p[4] = (short)f2bf(b.x); p[5] = (short)f2bf(b.y); p[6] = (short)f2bf(b.z); p[7] = (short)f2bf(b.w);
        *reinterpret_cast<short8*>(outt + (((size_t)(g * 8 + kb2)) << 9) + lane * 8) = p;
    }
    ss += __shfl_xor(ss, 16);
    ss += __shfl_xor(ss, 32);
    if (lane < 16) sumsq[g * 16 + lane] = ss;
}

// ---------------- MFMA screen: emit near-min candidates ----------------
__global__ __launch_bounds__(256) void k_screen(
    const float* __restrict__ z, const float* __restrict__ cbp,
    const unsigned short* __restrict__ z_t, const unsigned short* __restrict__ cb_t,
    const float* __restrict__ z2g, const float* __restrict__ e2g,
    unsigned* amin, unsigned long long* best,
    unsigned* counter, unsigned* list, unsigned C)
{
    __shared__ __align__(16) short lds[16384];
    char* ldsb = (char*)lds;
    __shared__ unsigned gbase_s;

    const int tid = threadIdx.x;
    const int lane = tid & 63;
    const int wave = tid >> 6;
    const int wm = wave & 1;
    const int wn = wave >> 1;
    const int lhi = lane >> 4;
    const int llo = lane & 15;

    const int bx = blockIdx.x;
    const int st = bx >> 6;
    const int wi = bx & 63;
    const int rt = (st & 15) * 8 + (wi >> 3);   // 0..127
    const int ct = (st >> 4) * 8 + (wi & 7);    // 0..63
    const int row0 = rt * 128;
    const int col0 = ct * 128;

    f32x4 acc[4][4];
    const f32x4 zero = {0.f, 0.f, 0.f, 0.f};
    #pragma unroll
    for (int i = 0; i < 4; ++i)
        #pragma unroll
        for (int j = 0; j < 4; ++j) acc[i][j] = zero;

    for (int ks = 0; ks < 4; ++ks) {
        __syncthreads();   // previous tile's readers done before async writes land
        // wave stages 4 A-chunks + 4 B-chunks, 1 KB each, via global_load_lds
        #pragma unroll
        for (int i = 0; i < 4; ++i) {
            const int c = wave * 4 + i;                 // 0..15: cl = c>>1, kk = c&1
            const int kb2 = ks * 2 + (c & 1);
            const int g_a = rt * 8 + (c >> 1);
            gload16((const char*)z_t + (((size_t)(g_a * 8 + kb2)) << 10) + lane * 16,
                    ldsb + c * 1024);
            const int g_b = ct * 8 + (c >> 1);
            gload16((const char*)cb_t + (((size_t)(g_b * 8 + kb2)) << 10) + lane * 16,
                    ldsb + 16384 + c * 1024);
        }
        __syncthreads();   // compiler drains vmcnt(0) before barrier -> tile ready
        #pragma unroll
        for (int kk = 0; kk < 2; ++kk) {
            short8 af[4], bf[4];
            #pragma unroll
            for (int f = 0; f < 4; ++f) {
                const int ca = (wm * 4 + f) * 2 + kk;
                af[f] = *reinterpret_cast<const short8*>(ldsb + ca * 1024 + lane * 16);
                const int cc = (wn * 4 + f) * 2 + kk;
                bf[f] = *reinterpret_cast<const short8*>(ldsb + 16384 + cc * 1024 + lane * 16);
            }
            #pragma unroll
            for (int fm = 0; fm < 4; ++fm)
                #pragma unroll
                for (int fn = 0; fn < 4; ++fn)
                    acc[fm][fn] = __builtin_amdgcn_mfma_f32_16x16x32_bf16(af[fm], bf[fn], acc[fm][fn], 0, 0, 0);
        }
    }

    // ---- epilogue ----
    __syncthreads();
    float* rowmin = (float*)ldsb;          // [2][128]
    float* thrbuf = (float*)(ldsb + 1024); // [128]
    unsigned* lcnt = (unsigned*)(ldsb + 2048);
    unsigned* llist = (unsigned*)(ldsb + 2064);

    if (tid == 0) *lcnt = 0u;
    const int cbase = col0 + wn * 64;
    float e2c[4];
    #pragma unroll
    for (int fn = 0; fn < 4; ++fn) e2c[fn] = e2g[cbase + fn * 16 + llo];

    // pass 1: per-row block-local min
    #pragma unroll
    for (int fm = 0; fm < 4; ++fm) {
        #pragma unroll
        for (int rg = 0; rg < 4; ++rg) {
            const int rl_ = wm * 64 + fm * 16 + lhi * 4 + rg;
            const float z2v = z2g[row0 + rl_];
            float m = z2v + e2c[0] - 2.0f * acc[fm][0][rg];
            #pragma unroll
            for (int fn = 1; fn < 4; ++fn)
                m = fminf(m, z2v + e2c[fn] - 2.0f * acc[fm][fn][rg]);
            #pragma unroll
            for (int off = 1; off < 16; off <<= 1) m = fminf(m, __shfl_xor(m, off));
            if (llo == 0) rowmin[wn * 128 + rl_] = m;
        }
    }
    __syncthreads();
    if (tid < 128) {
        const float m2 = fminf(rowmin[tid], rowmin[128 + tid]);
        const unsigned cur = amin[row0 + tid];
        unsigned old = cur;
        if (__float_as_uint(m2) < cur) old = atomicMin(&amin[row0 + tid], __float_as_uint(m2));
        thrbuf[tid] = fminf(__uint_as_float(old), m2) + MARGIN;
    }
    __syncthreads();

    // pass 2: emit candidates
    #pragma unroll
    for (int fm = 0; fm < 4; ++fm) {
        #pragma unroll
        for (int rg = 0; rg < 4; ++rg) {
            const int rl_ = wm * 64 + fm * 16 + lhi * 4 + rg;
            const int grow = row0 + rl_;
            const float z2v = z2g[grow];
            const float thr = thrbuf[rl_];
            #pragma unroll
            for (int fn = 0; fn < 4; ++fn) {
                const float d = z2v + e2c[fn] - 2.0f * acc[fm][fn][rg];
                if (d <= thr) {
                    const unsigned v = ((unsigned)grow << 13) | (unsigned)(cbase + fn * 16 + llo);
                    const unsigned slot = atomicAdd(lcnt, 1u);
                    if (slot < BLKLIST) llist[slot] = v;
                    else exact_rescore(z, cbp, z2g, e2g, grow, v & 8191u, best);
                }
            }
        }
    }
    __syncthreads();
    const unsigned bc = min(*lcnt, (unsigned)BLKLIST);
    if (tid == 0 && bc) gbase_s = atomicAdd(counter, bc);
    __syncthreads();
    for (unsigned i = tid; i < bc; i += 256) {
        const unsigned v = llist[i];
        const unsigned slot = gbase_s + i;
        if (slot < C) list[slot] = v;
        else exact_rescore(z, cbp, z2g, e2g, (int)(v >> 13), (int)(v & 8191u), best);
    }
}

// ---------------- exact rescore of candidate list (wave per candidate) ----------------
__global__ __launch_bounds__(256) void k_rescore(
    const float* __restrict__ z, const float* __restrict__ cbp,
    const float* __restrict__ z2g, const float* __restrict__ e2g,
    const unsigned* __restrict__ list, const unsigned* __restrict__ counter, unsigned C,
    unsigned long long* best)
{
    const unsigned n = min(counter[0], C);
    const unsigned wid = (blockIdx.x * blockDim.x + threadIdx.x) >> 6;
    const unsigned nw = (gridDim.x * blockDim.x) >> 6;
    const int lane = threadIdx.x & 63;
    for (unsigned i = wid; i < n; i += nw) {
        const unsigned v = list[i];
        const unsigned row = v >> 13, col = v & 8191u;
        const float4 a = *reinterpret_cast<const float4*>(z + (size_t)row * DDIM + lane * 4);
        const float4 b = *reinterpret_cast<const float4*>(cbp + (size_t)col * DDIM + lane * 4);
        float s = fmaf(a.x, b.x, fmaf(a.y, b.y, fmaf(a.z, b.z, a.w * b.w)));
        #pragma unroll
        for (int off = 1; off < 64; off <<= 1) s += __shfl_xor(s, off);
        if (lane == 0) {
            const float de = z2g[row] + e2g[col] - 2.0f * s;
            const unsigned long long key =
                ((unsigned long long)__float_as_uint(de) << 32) | col;
            atomicMin(&best[row], key);
        }
    }
}

// ---------------- gather + z_st + loss ----------------
__global__ __launch_bounds__(1024) void k_gather(
    const float* __restrict__ z, const float* __restrict__ cbp,
    const unsigned long long* __restrict__ best,
    float* __restrict__ out, float* __restrict__ accum)
{
    __shared__ float wsum[16];
    const int tid = threadIdx.x;
    const int row = blockIdx.x * 16 + (tid >> 6);
    const int lane = tid & 63;
    const unsigned k = (unsigned)(best[row] & 0xFFFFFFFFull);
    const float4 ze = *reinterpret_cast<const float4*>(z + (size_t)row * DDIM + lane * 4);
    const float4 cq = *reinterpret_cast<const float4*>(cbp + (size_t)k * DDIM + lane * 4);
    float4 zst;
    zst.x = ze.x + (cq.x - ze.x); zst.y = ze.y + (cq.y - ze.y);
    zst.z = ze.z + (cq.z - ze.z); zst.w = ze.w + (cq.w - ze.w);
    *reinterpret_cast<float4*>(out + (size_t)row * DDIM + lane * 4) = zst;
    const float dx = cq.x - ze.x, dy = cq.y - ze.y, dz = cq.z - ze.z, dw = cq.w - ze.w;
    float s = dx * dx + dy * dy + dz * dz + dw * dw;
    #pragma unroll
    for (int off = 32; off > 0; off >>= 1) s += __shfl_down(s, off);
    if (lane == 0) {
        wsum[tid >> 6] = s;
        out[(size_t)NROWS * DDIM + row] = (float)k;
    }
    __syncthreads();
    if (tid == 0) {
        float tot = 0.f;
        #pragma unroll
        for (int i = 0; i < 16; ++i) tot += wsum[i];
        atomicAdd(accum, tot);
    }
}

// ---------------- final scalars ----------------
__global__ void k_final(const float* __restrict__ accum, float* __restrict__ out) {
    const float m = accum[0] / (float)(NROWS * DDIM);
    out[(size_t)NROWS * DDIM + NROWS + 0] = m;
    out[(size_t)NROWS * DDIM + NROWS + 1] = m;
}

extern "C" void kernel_launch(void* const* d_in, const int* in_sizes, int n_in,
                              void* d_out, int out_size, void* d_ws, size_t ws_size,
                              hipStream_t stream)
{
    const float* z  = (const float*)d_in[0];
    const float* cb = (const float*)d_in[1];
    float* out = (float*)d_out;

    // bf16 pre-tiled scratch lives in d_out's z_st region (12 MB of 16.8 MB),
    // consumed by k_screen and fully overwritten afterwards by k_gather.
    unsigned short* z_t  = (unsigned short*)d_out;                      // 8 MB
    unsigned short* cb_t = (unsigned short*)((char*)d_out + 8388608);   // 4 MB

    char* ws = (char*)d_ws;
    unsigned long long* best = (unsigned long long*)ws;            // 131072 B
    unsigned* amin = (unsigned*)(ws + 131072);                     // 65536 B
    float* e2    = (float*)(ws + 131072 + 65536);                  // 32768 B
    float* z2    = (float*)(ws + 131072 + 65536 + 32768);          // 65536 B
    float* accum   = (float*)(ws + 294912);
    unsigned* counter = (unsigned*)(ws + 294916);
    unsigned* list = (unsigned*)(ws + 295936);
    unsigned C = 0;
    if (ws_size > 295936 + 16) {
        size_t c = (ws_size - 295936) / 4;
        if (c > 4194304) c = 4194304;
        C = (unsigned)c;
    }

    k_init<<<(NROWS + 255) / 256, 256, 0, stream>>>(best, amin, accum, counter);
    k_convert<<<NROWS / 16 / 4, 256, 0, stream>>>(z, z_t, z2, NROWS / 16);
    k_convert<<<KCODES / 16 / 4, 256, 0, stream>>>(cb, cb_t, e2, KCODES / 16);
    k_screen<<<8192, 256, 0, stream>>>(z, cb, z_t, cb_t, z2, e2, amin, best, counter, list, C);
    k_rescore<<<1024, 256, 0, stream>>>(z, cb, z2, e2, list, counter, C, best);
    k_gather<<<NROWS / 16, 1024, 0, stream>>>(z, cb, best, out, accum);
    k_final<<<1, 1, 0, stream>>>(accum, out);
}